// Round 1
// baseline (1036.518 us; speedup 1.0000x reference)
//
#include <hip/hip_runtime.h>
#include <hip/hip_bf16.h>
#include <math.h>

#define Bd 2
#define Nd 1024
#define Dd 1024
#define Hh 16
#define Hd 64
#define DE 64
#define DR 128
#define EPSf 1e-6f
#define NPB 8
#define KC 32

// ---------------- Kernel 1: witness projections ----------------
__global__ void witness_kernel(const float* __restrict__ x,
    const float* __restrict__ WE, const float* __restrict__ bE,
    const float* __restrict__ WS, const float* __restrict__ bS,
    const float* __restrict__ WH, const float* __restrict__ bH,
    const float* __restrict__ Wrff, const float* __restrict__ brff,
    float* __restrict__ wEo, float* __restrict__ wSo, float* __restrict__ wHo,
    float* __restrict__ zo, float* __restrict__ sqo)
{
    const int e = threadIdx.x;           // 0..63
    int idx = blockIdx.x;
    const int NC = Nd / NPB;             // 128
    int nc = idx % NC;
    int h = (idx / NC) % Hh;
    int b = idx / (NC * Hh);
    int n0 = nc * NPB;

    __shared__ float xs[NPB][Hd];
    #pragma unroll
    for (int r = 0; r < NPB; r++)
        xs[r][e] = x[((size_t)b * Nd + n0 + r) * Dd + h * Hd + e];
    __syncthreads();

    size_t rowbase = ((size_t)(b * Hh + h) * Nd + n0);

    // ---- Euclidean ----
    {
        float acc[NPB];
        #pragma unroll
        for (int r = 0; r < NPB; r++) acc[r] = 0.f;
        const float* Wp = WE + (size_t)h * Hd * DE + e;
        for (int d = 0; d < Hd; d++) {
            float w = Wp[(size_t)d * DE];
            #pragma unroll
            for (int r = 0; r < NPB; r++) acc[r] = fmaf(xs[r][d], w, acc[r]);
        }
        float bb = bE[h * DE + e];
        #pragma unroll
        for (int r = 0; r < NPB; r++) {
            float v = acc[r] + bb;
            wEo[(rowbase + r) * DE + e] = v;
            float s = v * v;
            for (int o = 32; o > 0; o >>= 1) s += __shfl_xor(s, o, 64);
            if (e == 0) sqo[(rowbase + r) * 4 + 0] = s;
        }
    }
    // ---- Spherical ----
    {
        float acc[NPB];
        #pragma unroll
        for (int r = 0; r < NPB; r++) acc[r] = 0.f;
        const float* Wp = WS + (size_t)h * Hd * DE + e;
        for (int d = 0; d < Hd; d++) {
            float w = Wp[(size_t)d * DE];
            #pragma unroll
            for (int r = 0; r < NPB; r++) acc[r] = fmaf(xs[r][d], w, acc[r]);
        }
        float bb = bS[h * DE + e];
        #pragma unroll
        for (int r = 0; r < NPB; r++) {
            float v = acc[r] + bb;
            float s = v * v;
            for (int o = 32; o > 0; o >>= 1) s += __shfl_xor(s, o, 64);
            float nrm = sqrtf(s);
            wSo[(rowbase + r) * DE + e] = v / (nrm + EPSf);
        }
    }
    // ---- Hyperbolic ----
    {
        float acc[NPB];
        #pragma unroll
        for (int r = 0; r < NPB; r++) acc[r] = 0.f;
        const float* Wp = WH + (size_t)h * Hd * DE + e;
        for (int d = 0; d < Hd; d++) {
            float w = Wp[(size_t)d * DE];
            #pragma unroll
            for (int r = 0; r < NPB; r++) acc[r] = fmaf(xs[r][d], w, acc[r]);
        }
        float bb = bH[h * DE + e];
        #pragma unroll
        for (int r = 0; r < NPB; r++) {
            float u = acc[r] + bb;
            float s = u * u;
            for (int o = 32; o > 0; o >>= 1) s += __shfl_xor(s, o, 64);
            float un = sqrtf(s);
            float sc = tanhf(un) / (un + EPSf);
            float w = sc * u;
            wHo[(rowbase + r) * DE + e] = w;
            float s2 = w * w;
            for (int o = 32; o > 0; o >>= 1) s2 += __shfl_xor(s2, o, 64);
            if (e == 0) {
                sqo[(rowbase + r) * 4 + 1] = s2;
                sqo[(rowbase + r) * 4 + 2] = fminf(fmaxf(s2, 0.f), 1.f - 1e-5f);
            }
        }
    }
    // ---- RFF ----
    {
        float sF[NPB];
        #pragma unroll
        for (int r = 0; r < NPB; r++) sF[r] = 0.f;
        #pragma unroll
        for (int half = 0; half < 2; half++) {
            int col = e + 64 * half;
            float acc[NPB];
            #pragma unroll
            for (int r = 0; r < NPB; r++) acc[r] = 0.f;
            const float* Wp = Wrff + (size_t)h * Hd * DR + col;
            for (int d = 0; d < Hd; d++) {
                float w = Wp[(size_t)d * DR];
                #pragma unroll
                for (int r = 0; r < NPB; r++) acc[r] = fmaf(xs[r][d], w, acc[r]);
            }
            float bb = brff[h * DR + col];
            #pragma unroll
            for (int r = 0; r < NPB; r++) {
                float zv = 0.125f * cosf(acc[r] + bb);
                zo[(rowbase + r) * DR + col] = zv;
                sF[r] += zv * zv;
            }
        }
        #pragma unroll
        for (int r = 0; r < NPB; r++) {
            float s = sF[r];
            for (int o = 32; o > 0; o >>= 1) s += __shfl_xor(s, o, 64);
            if (e == 0) sqo[(rowbase + r) * 4 + 3] = s;
        }
    }
}

// ---------------- Kernel 2/4: C[i][j] = sum_k A[i][k]*W[j][k] + bias[j] ----------------
// M=2048 (grid.y*64), K=1024, J=1024 (grid.x*64)
__global__ __launch_bounds__(256) void gemm_kernel(const float* __restrict__ A,
    const float* __restrict__ W, const float* __restrict__ bias, float* __restrict__ C)
{
    __shared__ float At[16][68];
    __shared__ float Wt[16][68];
    int tid = threadIdx.x, tx = tid & 15, ty = tid >> 4;
    int i0 = blockIdx.y * 64, j0 = blockIdx.x * 64;
    int li = tid >> 2, lk = (tid & 3) * 4;
    float acc[4][4] = {};
    for (int kc = 0; kc < 1024; kc += 16) {
        float4 av = *(const float4*)&A[(size_t)(i0 + li) * 1024 + kc + lk];
        float4 wv = *(const float4*)&W[(size_t)(j0 + li) * 1024 + kc + lk];
        __syncthreads();
        At[lk + 0][li] = av.x; At[lk + 1][li] = av.y; At[lk + 2][li] = av.z; At[lk + 3][li] = av.w;
        Wt[lk + 0][li] = wv.x; Wt[lk + 1][li] = wv.y; Wt[lk + 2][li] = wv.z; Wt[lk + 3][li] = wv.w;
        __syncthreads();
        #pragma unroll
        for (int kk = 0; kk < 16; kk++) {
            float4 a4 = *(const float4*)&At[kk][4 * ty];
            float4 w4 = *(const float4*)&Wt[kk][4 * tx];
            const float* ap = (const float*)&a4;
            const float* wp = (const float*)&w4;
            #pragma unroll
            for (int i = 0; i < 4; i++)
                #pragma unroll
                for (int j = 0; j < 4; j++)
                    acc[i][j] = fmaf(ap[i], wp[j], acc[i][j]);
        }
    }
    #pragma unroll
    for (int i = 0; i < 4; i++) {
        size_t ci = (size_t)(i0 + 4 * ty + i) * 1024 + j0 + 4 * tx;
        float4 o;
        o.x = acc[i][0] + bias[j0 + 4 * tx + 0];
        o.y = acc[i][1] + bias[j0 + 4 * tx + 1];
        o.z = acc[i][2] + bias[j0 + 4 * tx + 2];
        o.w = acc[i][3] + bias[j0 + 4 * tx + 3];
        *(float4*)&C[ci] = o;
    }
}

// ---------------- Kernel 3: distances + online softmax + PV ----------------
__global__ __launch_bounds__(256) void attn_kernel(
    const float* __restrict__ wE, const float* __restrict__ wS,
    const float* __restrict__ wH, const float* __restrict__ zb,
    const float* __restrict__ sq, const float* __restrict__ vbuf,
    const int* __restrict__ mask,
    const float* __restrict__ alpha, const float* __restrict__ beta,
    const float* __restrict__ gamma_, const float* __restrict__ delta,
    const float* __restrict__ temperature,
    float* __restrict__ aout)
{
    int qt = blockIdx.x, h = blockIdx.y, b = blockIdx.z;
    int q0 = qt * 64;
    size_t bh = (size_t)b * Hh + h;
    const float* baseE = wE + bh * Nd * 64;
    const float* baseS = wS + bh * Nd * 64;
    const float* baseH = wH + bh * Nd * 64;
    const float* baseF = zb + bh * Nd * 128;

    __shared__ float qbuf[KC][68];
    __shared__ float kbuf[KC][68];
    __shared__ float Pb[64][68];
    __shared__ float Vt[64][64];
    __shared__ float sqq[64][4];
    __shared__ float sqk[64][4];
    __shared__ float mrow[64], lrow[64], frow[64];
    __shared__ int mk[64];

    int tid = threadIdx.x, tx = tid & 15, ty = tid >> 4;

    if (tid < 64) {
        #pragma unroll
        for (int c = 0; c < 4; c++) sqq[tid][c] = sq[(bh * Nd + q0 + tid) * 4 + c];
        mrow[tid] = -INFINITY;
        lrow[tid] = 0.f;
    }
    float O[4][4] = {};
    float al = alpha[h], be = beta[h], ga = gamma_[h], de = delta[h];
    float itmp = 1.f / temperature[h];

    for (int k0 = 0; k0 < Nd; k0 += 64) {
        __syncthreads();  // protect Pb/Vt/sqk from previous iteration's reads
        if (tid < 64) {
            #pragma unroll
            for (int c = 0; c < 4; c++) sqk[tid][c] = sq[(bh * Nd + k0 + tid) * 4 + c];
            mk[tid] = mask[b * Nd + k0 + tid];
        }
        // V tile load (64 x 64)
        #pragma unroll
        for (int it2 = 0; it2 < 16; it2++) {
            int e2 = tid + 256 * it2;
            int m = e2 >> 6, dd = e2 & 63;
            Vt[m][dd] = vbuf[((size_t)b * Nd + k0 + m) * Dd + h * Hd + dd];
        }

        float accE[4][4] = {}, accS[4][4] = {}, accH[4][4] = {}, accF[4][4] = {};

#define GRAM(ACC, BASE, SD)                                                      \
        {                                                                        \
            const float* qp = (BASE) + (size_t)q0 * (SD);                        \
            const float* kp = (BASE) + (size_t)k0 * (SD);                        \
            for (int c0 = 0; c0 < (SD); c0 += KC) {                              \
                __syncthreads();                                                 \
                for (int e2 = tid; e2 < 64 * KC; e2 += 256) {                    \
                    int r = e2 >> 5, kk = e2 & 31;                               \
                    qbuf[kk][r] = qp[(size_t)r * (SD) + c0 + kk];                \
                    kbuf[kk][r] = kp[(size_t)r * (SD) + c0 + kk];                \
                }                                                                \
                __syncthreads();                                                 \
                _Pragma("unroll")                                                \
                for (int kk = 0; kk < KC; kk++) {                                \
                    float4 a4 = *(const float4*)&qbuf[kk][4 * ty];               \
                    float4 b4 = *(const float4*)&kbuf[kk][4 * tx];               \
                    const float* ap = (const float*)&a4;                         \
                    const float* bp = (const float*)&b4;                         \
                    _Pragma("unroll")                                            \
                    for (int i = 0; i < 4; i++)                                  \
                        _Pragma("unroll")                                        \
                        for (int j = 0; j < 4; j++)                              \
                            ACC[i][j] = fmaf(ap[i], bp[j], ACC[i][j]);           \
                }                                                                \
            }                                                                    \
        }

        GRAM(accE, baseE, 64)
        GRAM(accS, baseS, 64)
        GRAM(accH, baseH, 64)
        GRAM(accF, baseF, 128)
#undef GRAM

        // distance -> logits
        #pragma unroll
        for (int i = 0; i < 4; i++) {
            int q = 4 * ty + i;
            #pragma unroll
            for (int j = 0; j < 4; j++) {
                int m = 4 * tx + j;
                float sE = sqq[q][0] + sqk[m][0] - 2.f * accE[i][j];
                float dE = sqrtf(fmaxf(sE, 0.f) + EPSf);
                float cosv = fminf(fmaxf(accS[i][j], -1.f + EPSf), 1.f - EPSf);
                float dS = acosf(cosv);
                float d2H = fmaxf(sqq[q][1] + sqk[m][1] - 2.f * accH[i][j], 0.f);
                float denom = (1.f - sqq[q][2]) * (1.f - sqk[m][2]);
                float ar = 1.f + 2.f * d2H / (denom + EPSf);
                float dH = acoshf(fmaxf(ar, 1.f + EPSf));
                float sF = sqq[q][3] + sqk[m][3] - 2.f * accF[i][j];
                float dF = sqrtf(fmaxf(sF, 0.f) + EPSf);
                float dist = (al * dE + be * dS + ga * dH + de * dF) * itmp;
                Pb[q][m] = (mk[m] > 0) ? -dist : -1e9f;
            }
        }
        __syncthreads();

        // online softmax: 4 threads per row
        {
            int r = tid >> 2, c0 = (tid & 3) * 16;
            float4 pv4[4];
            float lm = -INFINITY;
            #pragma unroll
            for (int k4 = 0; k4 < 4; k4++) {
                pv4[k4] = *(const float4*)&Pb[r][c0 + 4 * k4];
                lm = fmaxf(lm, fmaxf(fmaxf(pv4[k4].x, pv4[k4].y), fmaxf(pv4[k4].z, pv4[k4].w)));
            }
            lm = fmaxf(lm, __shfl_xor(lm, 1, 64));
            lm = fmaxf(lm, __shfl_xor(lm, 2, 64));
            float mold = mrow[r];
            float mnew = fmaxf(mold, lm);
            float f = expf(mold - mnew);
            float ssum = 0.f;
            #pragma unroll
            for (int k4 = 0; k4 < 4; k4++) {
                float4 t4 = pv4[k4];
                t4.x = expf(t4.x - mnew);
                t4.y = expf(t4.y - mnew);
                t4.z = expf(t4.z - mnew);
                t4.w = expf(t4.w - mnew);
                ssum += t4.x + t4.y + t4.z + t4.w;
                *(float4*)&Pb[r][c0 + 4 * k4] = t4;
            }
            ssum += __shfl_xor(ssum, 1, 64);
            ssum += __shfl_xor(ssum, 2, 64);
            if ((tid & 3) == 0) {
                mrow[r] = mnew;
                lrow[r] = lrow[r] * f + ssum;
                frow[r] = f;
            }
        }
        __syncthreads();

        // PV accumulation
        {
            float fr0 = frow[4 * ty + 0], fr1 = frow[4 * ty + 1];
            float fr2 = frow[4 * ty + 2], fr3 = frow[4 * ty + 3];
            #pragma unroll
            for (int j = 0; j < 4; j++) {
                O[0][j] *= fr0; O[1][j] *= fr1; O[2][j] *= fr2; O[3][j] *= fr3;
            }
            for (int m0 = 0; m0 < 64; m0 += 4) {
                float4 p0 = *(const float4*)&Pb[4 * ty + 0][m0];
                float4 p1 = *(const float4*)&Pb[4 * ty + 1][m0];
                float4 p2 = *(const float4*)&Pb[4 * ty + 2][m0];
                float4 p3 = *(const float4*)&Pb[4 * ty + 3][m0];
                const float* pp0 = (const float*)&p0;
                const float* pp1 = (const float*)&p1;
                const float* pp2 = (const float*)&p2;
                const float* pp3 = (const float*)&p3;
                #pragma unroll
                for (int mm = 0; mm < 4; mm++) {
                    float4 v4 = *(const float4*)&Vt[m0 + mm][4 * tx];
                    const float* vp = (const float*)&v4;
                    #pragma unroll
                    for (int j = 0; j < 4; j++) {
                        O[0][j] = fmaf(pp0[mm], vp[j], O[0][j]);
                        O[1][j] = fmaf(pp1[mm], vp[j], O[1][j]);
                        O[2][j] = fmaf(pp2[mm], vp[j], O[2][j]);
                        O[3][j] = fmaf(pp3[mm], vp[j], O[3][j]);
                    }
                }
            }
        }
    }

    __syncthreads();
    #pragma unroll
    for (int i = 0; i < 4; i++) {
        float invl = 1.f / lrow[4 * ty + i];
        float4 o4;
        o4.x = O[i][0] * invl;
        o4.y = O[i][1] * invl;
        o4.z = O[i][2] * invl;
        o4.w = O[i][3] * invl;
        *(float4*)&aout[((size_t)b * Nd + q0 + 4 * ty + i) * Dd + h * Hd + 4 * tx] = o4;
    }
}

extern "C" void kernel_launch(void* const* d_in, const int* in_sizes, int n_in,
                              void* d_out, int out_size, void* d_ws, size_t ws_size,
                              hipStream_t stream) {
    const float* x    = (const float*)d_in[0];
    const int*   mask = (const int*)d_in[1];
    const float* WE   = (const float*)d_in[2];
    const float* bE   = (const float*)d_in[3];
    const float* WS   = (const float*)d_in[4];
    const float* bS   = (const float*)d_in[5];
    const float* WH   = (const float*)d_in[6];
    const float* bH   = (const float*)d_in[7];
    const float* Wrff = (const float*)d_in[8];
    const float* brff = (const float*)d_in[9];
    const float* alpha = (const float*)d_in[10];
    const float* beta  = (const float*)d_in[11];
    const float* gamma_ = (const float*)d_in[12];
    const float* delta = (const float*)d_in[13];
    const float* temperature = (const float*)d_in[14];
    const float* Wv = (const float*)d_in[15];
    const float* bv = (const float*)d_in[16];
    const float* Wo = (const float*)d_in[17];
    const float* bo = (const float*)d_in[18];

    float* ws = (float*)d_ws;
    size_t R = (size_t)Bd * Hh * Nd;          // 32768 rows
    float* wEb = ws;
    float* wSb = wEb + R * 64;
    float* wHb = wSb + R * 64;
    float* zbb = wHb + R * 64;
    float* sqb = zbb + R * 128;
    float* vb  = sqb + R * 4;
    float* ab  = vb + (size_t)Bd * Nd * Dd;

    witness_kernel<<<dim3(Bd * Hh * (Nd / NPB)), 64, 0, stream>>>(
        x, WE, bE, WS, bS, WH, bH, Wrff, brff, wEb, wSb, wHb, zbb, sqb);

    gemm_kernel<<<dim3(16, 32), 256, 0, stream>>>(x, Wv, bv, vb);

    attn_kernel<<<dim3(Nd / 64, Hh, Bd), 256, 0, stream>>>(
        wEb, wSb, wHb, zbb, sqb, vb, mask,
        alpha, beta, gamma_, delta, temperature, ab);

    gemm_kernel<<<dim3(16, 32), 256, 0, stream>>>(ab, Wo, bo, (float*)d_out);
}

// Round 2
// 270.113 us; speedup vs baseline: 3.8373x; 3.8373x over previous
//
#include <hip/hip_runtime.h>
#include <hip/hip_bf16.h>
#include <math.h>
#include <stdint.h>

#define Bd 2
#define Nd 1024
#define Dd 1024
#define Hh 16
#define EPSf 1e-6f
#define NPB 8

typedef short s8v __attribute__((ext_vector_type(8)));
typedef float f16v __attribute__((ext_vector_type(16)));
typedef float f4v __attribute__((ext_vector_type(4)));

#define MFMA32x32(A,B,C) __builtin_amdgcn_mfma_f32_32x32x16_bf16(A,B,C,0,0,0)
#define MFMA16x16(A,B,C) __builtin_amdgcn_mfma_f32_16x16x32_bf16(A,B,C,0,0,0)

__device__ __forceinline__ void gl_lds16(const void* g, void* l) {
    __builtin_amdgcn_global_load_lds((const __attribute__((address_space(1))) unsigned int*)g,
                                     (__attribute__((address_space(3))) unsigned int*)l, 16, 0, 0);
}

__device__ __forceinline__ unsigned short bf16bits(float v) {
    __hip_bfloat16 h = __float2bfloat16(v);
    return *(unsigned short*)&h;
}
__device__ __forceinline__ float bf16rt(float v) {   // round-trip through bf16
    __hip_bfloat16 h = __float2bfloat16(v);
    return __bfloat162float(h);
}

// ---------------- Kernel 1: witness projections -> combined bf16 witness rows ----------------
// wit[row][320] bf16: [0:64)=wE, [64:128)=wS(normalized), [128:192)=wHb, [192:320)=z
// sq[row][4] f32: {|wE|^2, |wHb|^2, 1-clip(|wHb|^2), |z|^2}  (all from bf16-rounded values)
// xb: bf16 copy of x
__global__ void witness_kernel(const float* __restrict__ x,
    const float* __restrict__ WE, const float* __restrict__ bE,
    const float* __restrict__ WS, const float* __restrict__ bS,
    const float* __restrict__ WH, const float* __restrict__ bH,
    const float* __restrict__ Wrff, const float* __restrict__ brff,
    unsigned short* __restrict__ wit, float* __restrict__ sqo,
    unsigned short* __restrict__ xb)
{
    const int e = threadIdx.x;           // 0..63
    int idx = blockIdx.x;
    const int NC = Nd / NPB;             // 128
    int nc = idx % NC;
    int h = (idx / NC) % Hh;
    int b = idx / (NC * Hh);
    int n0 = nc * NPB;

    __shared__ float xs[NPB][64];
    #pragma unroll
    for (int r = 0; r < NPB; r++) {
        float xv = x[((size_t)b * Nd + n0 + r) * Dd + h * 64 + e];
        xs[r][e] = xv;
        xb[((size_t)b * Nd + n0 + r) * Dd + h * 64 + e] = bf16bits(xv);
    }
    __syncthreads();

    size_t rowbase = ((size_t)(b * Hh + h) * Nd + n0);

    // ---- Euclidean ----
    {
        float acc[NPB];
        #pragma unroll
        for (int r = 0; r < NPB; r++) acc[r] = 0.f;
        const float* Wp = WE + (size_t)h * 64 * 64 + e;
        for (int d = 0; d < 64; d++) {
            float w = Wp[(size_t)d * 64];
            #pragma unroll
            for (int r = 0; r < NPB; r++) acc[r] = fmaf(xs[r][d], w, acc[r]);
        }
        float bb = bE[h * 64 + e];
        #pragma unroll
        for (int r = 0; r < NPB; r++) {
            float v = acc[r] + bb;
            float vf = bf16rt(v);
            wit[(rowbase + r) * 320 + e] = bf16bits(v);
            float s = vf * vf;
            for (int o = 32; o > 0; o >>= 1) s += __shfl_xor(s, o, 64);
            if (e == 0) sqo[(rowbase + r) * 4 + 0] = s;
        }
    }
    // ---- Spherical ----
    {
        float acc[NPB];
        #pragma unroll
        for (int r = 0; r < NPB; r++) acc[r] = 0.f;
        const float* Wp = WS + (size_t)h * 64 * 64 + e;
        for (int d = 0; d < 64; d++) {
            float w = Wp[(size_t)d * 64];
            #pragma unroll
            for (int r = 0; r < NPB; r++) acc[r] = fmaf(xs[r][d], w, acc[r]);
        }
        float bb = bS[h * 64 + e];
        #pragma unroll
        for (int r = 0; r < NPB; r++) {
            float v = acc[r] + bb;
            float s = v * v;
            for (int o = 32; o > 0; o >>= 1) s += __shfl_xor(s, o, 64);
            float nrm = sqrtf(s);
            wit[(rowbase + r) * 320 + 64 + e] = bf16bits(v / (nrm + EPSf));
        }
    }
    // ---- Hyperbolic ----
    {
        float acc[NPB];
        #pragma unroll
        for (int r = 0; r < NPB; r++) acc[r] = 0.f;
        const float* Wp = WH + (size_t)h * 64 * 64 + e;
        for (int d = 0; d < 64; d++) {
            float w = Wp[(size_t)d * 64];
            #pragma unroll
            for (int r = 0; r < NPB; r++) acc[r] = fmaf(xs[r][d], w, acc[r]);
        }
        float bb = bH[h * 64 + e];
        #pragma unroll
        for (int r = 0; r < NPB; r++) {
            float u = acc[r] + bb;
            float s = u * u;
            for (int o = 32; o > 0; o >>= 1) s += __shfl_xor(s, o, 64);
            float un = sqrtf(s);
            float sc = tanhf(un) / (un + EPSf);
            float w = sc * u;
            float wf = bf16rt(w);
            wit[(rowbase + r) * 320 + 128 + e] = bf16bits(w);
            float s2 = wf * wf;
            for (int o = 32; o > 0; o >>= 1) s2 += __shfl_xor(s2, o, 64);
            if (e == 0) {
                sqo[(rowbase + r) * 4 + 1] = s2;
                sqo[(rowbase + r) * 4 + 2] = 1.f - fminf(fmaxf(s2, 0.f), 1.f - 1e-5f);
            }
        }
    }
    // ---- RFF ----
    {
        float sF[NPB];
        #pragma unroll
        for (int r = 0; r < NPB; r++) sF[r] = 0.f;
        #pragma unroll
        for (int half = 0; half < 2; half++) {
            int col = e + 64 * half;
            float acc[NPB];
            #pragma unroll
            for (int r = 0; r < NPB; r++) acc[r] = 0.f;
            const float* Wp = Wrff + (size_t)h * 64 * 128 + col;
            for (int d = 0; d < 64; d++) {
                float w = Wp[(size_t)d * 128];
                #pragma unroll
                for (int r = 0; r < NPB; r++) acc[r] = fmaf(xs[r][d], w, acc[r]);
            }
            float bb = brff[h * 128 + col];
            #pragma unroll
            for (int r = 0; r < NPB; r++) {
                float zv = 0.125f * cosf(acc[r] + bb);
                float zf = bf16rt(zv);
                wit[(rowbase + r) * 320 + 192 + col] = bf16bits(zv);
                sF[r] += zf * zf;
            }
        }
        #pragma unroll
        for (int r = 0; r < NPB; r++) {
            float s = sF[r];
            for (int o = 32; o > 0; o >>= 1) s += __shfl_xor(s, o, 64);
            if (e == 0) sqo[(rowbase + r) * 4 + 3] = s;
        }
    }
}

// ---------------- convert f32 -> bf16 ----------------
__global__ void cvt_kernel(const float* __restrict__ src, unsigned short* __restrict__ dst, int n)
{
    int i = (blockIdx.x * blockDim.x + threadIdx.x) * 4;
    if (i < n) {
        float4 v = *(const float4*)(src + i);
        ushort4 o;
        o.x = bf16bits(v.x); o.y = bf16bits(v.y); o.z = bf16bits(v.z); o.w = bf16bits(v.w);
        *(ushort4*)(dst + i) = o;
    }
}

// ---------------- bf16 MFMA GEMM: C[M x 1024] = A[M x 1024] * W[1024 x 1024]^T + bias ----------------
// MODE 0: write f32 row-major to outF.  MODE 1: write bf16 to vt[bh][d][n] layout.
template<int MODE>
__global__ __launch_bounds__(256) void gemm_bf16_kernel(
    const unsigned short* __restrict__ A, const unsigned short* __restrict__ Bw,
    const float* __restrict__ bias, float* __restrict__ outF, unsigned short* __restrict__ outV)
{
    __shared__ __align__(16) char sm[24576];   // 2 x (At 8192 + Bt 4096)
    int tid = threadIdx.x, lane = tid & 63, w = tid >> 6;
    int wm = w >> 1, wn = w & 1;
    int i0 = blockIdx.y * 128, j0 = blockIdx.x * 64;
    const char* Ab = (const char*)A;
    const char* Bb = (const char*)Bw;

    f4v acc[4][2];
    #pragma unroll
    for (int i = 0; i < 4; i++) { acc[i][0] = (f4v){}; acc[i][1] = (f4v){}; }

    auto stage = [&](int kt, int buf) {
        char* atb = sm + buf * 12288;
        char* btb = atb + 8192;
        #pragma unroll
        for (int j = 0; j < 2; j++) {
            int id = w * 128 + j * 64 + lane;
            int row = id >> 2, u = id & 3;
            gl_lds16(Ab + (size_t)(i0 + row) * 2048 + kt * 64 + u * 16,
                     atb + w * 2048 + j * 1024);
        }
        {
            int id = w * 64 + lane;
            int row = id >> 2, u = id & 3;
            gl_lds16(Bb + (size_t)(j0 + row) * 2048 + kt * 64 + u * 16,
                     btb + w * 1024);
        }
    };

    stage(0, 0);
    __syncthreads();
    for (int kt = 0; kt < 32; kt++) {
        int buf = kt & 1;
        if (kt < 31) stage(kt + 1, buf ^ 1);
        const char* atb = sm + buf * 12288;
        const char* btb = atb + 8192;
        s8v af[4], bf[2];
        #pragma unroll
        for (int fi = 0; fi < 4; fi++)
            af[fi] = *(const s8v*)(atb + (wm * 64 + fi * 16 + (lane & 15)) * 64 + (lane >> 4) * 16);
        #pragma unroll
        for (int fj = 0; fj < 2; fj++)
            bf[fj] = *(const s8v*)(btb + (wn * 32 + fj * 16 + (lane & 15)) * 64 + (lane >> 4) * 16);
        #pragma unroll
        for (int fi = 0; fi < 4; fi++)
            #pragma unroll
            for (int fj = 0; fj < 2; fj++)
                acc[fi][fj] = MFMA16x16(af[fi], bf[fj], acc[fi][fj]);
        __syncthreads();
    }

    #pragma unroll
    for (int fi = 0; fi < 4; fi++)
        #pragma unroll
        for (int fj = 0; fj < 2; fj++)
            #pragma unroll
            for (int r = 0; r < 4; r++) {
                int grow = i0 + wm * 64 + fi * 16 + (lane >> 4) * 4 + r;
                int gcol = j0 + wn * 32 + fj * 16 + (lane & 15);
                float v = acc[fi][fj][r] + bias[gcol];
                if (MODE == 0) {
                    outF[(size_t)grow * 1024 + gcol] = v;
                } else {
                    int bb = grow >> 10, n = grow & 1023;
                    int hh = gcol >> 6, dd = gcol & 63;
                    outV[((size_t)(bb * 16 + hh) * 64 + dd) * 1024 + n] = bf16bits(v);
                }
            }
}

// ---------------- Kernel 3: MFMA distances + online softmax + MFMA PV ----------------
// block 256 = 4 waves: qsub = wid&1 (32 q-rows each), par = wid>>1 (even/odd k-tiles)
#define OFF_KT  0        // 2 x 20480
#define OFF_VT  40960    // 2 x 9216  (64 rows x 144B padded)
#define OFF_SQK 59392    // 2 x 512
#define OFF_MF  60416    // 2 x 128
#define OFF_SC  60672    // 4 x 128
#define OFF_ML  61184    // m/l/a/b: 4 x 256
__global__ __launch_bounds__(256, 2) void attn_kernel(
    const unsigned short* __restrict__ wit, const float* __restrict__ sqb,
    const unsigned short* __restrict__ vt, const int* __restrict__ mask,
    const float* __restrict__ al_, const float* __restrict__ be_,
    const float* __restrict__ ga_, const float* __restrict__ de_,
    const float* __restrict__ tp_,
    __hip_bfloat16* __restrict__ aout)
{
    __shared__ __align__(16) char sm[62208];
    int tid = threadIdx.x, lane = tid & 63;
    int wid = tid >> 6, qsub = wid & 1, par = wid >> 1;
    int h8 = lane >> 5, l31 = lane & 31, h4 = h8 * 4;
    int hh = blockIdx.y, bz = blockIdx.z;
    int bh = bz * Hh + hh;
    int q0 = blockIdx.x * 64;
    const char* witb = (const char*)wit + (size_t)bh * Nd * 640;

    // Q fragments (B-operand of swapped gram): 20 chunks of 16 features
    s8v qf[20];
    {
        const char* qrowp = witb + (size_t)(q0 + qsub * 32 + l31) * 640;
        #pragma unroll
        for (int c = 0; c < 20; c++)
            qf[c] = *(const s8v*)(qrowp + c * 32 + h8 * 16);
    }
    f4v sqq = *(const f4v*)(sqb + (size_t)(bh * Nd + q0 + qsub * 32 + l31) * 4);
    float al = al_[hh], be = be_[hh], ga = ga_[hh], de = de_[hh];
    float itmp = 1.f / tp_[hh];

    float m_run = -INFINITY, l_run = 0.f;
    f16v o0 = {}, o1 = {};

    char* KTg = sm + OFF_KT + par * 20480;
    char* VTg = sm + OFF_VT + par * 9216;
    const float* sqkLg = (const float*)(sm + OFF_SQK + par * 512);
    const float* mfLg = (const float*)(sm + OFF_MF + par * 128);
    float* scl = (float*)(sm + OFF_SC + wid * 128);
    int xorv = (l31 & 7) << 4;

    for (int it = 0; it < 16; it++) {
        int k0 = (it * 2 + par) * 32;
        // ---- stage K tile (pre-swizzled source -> linear LDS; read with XOR) ----
        #pragma unroll
        for (int j = 0; j < 10; j++) {
            int id = qsub * 640 + j * 64 + lane;
            int r = id / 40, u = id - r * 40;
            gl_lds16(witb + (size_t)(k0 + r) * 640 + ((u * 16) ^ ((r & 7) << 4)),
                     KTg + qsub * 10240 + j * 1024);
        }
        // ---- stage V tile (reg-staged into padded rows: 64 d-rows x 144B) ----
        {
            int tg = tid & 127;
            #pragma unroll
            for (int j = 0; j < 2; j++) {
                int id = tg * 2 + j;
                int row = id >> 2, u = id & 3;
                int4 d = *(const int4*)((const char*)vt + ((size_t)(bh * 64 + row) * 1024 + k0 + u * 8) * 2);
                *(int4*)(VTg + row * 144 + u * 16) = d;
            }
        }
        if (qsub == 0 && lane < 32)
            gl_lds16(sqb + (size_t)(bh * Nd + k0 + lane) * 4, sm + OFF_SQK + par * 512);
        if (qsub == 1 && lane < 32)
            *(float*)(sm + OFF_MF + par * 128 + lane * 4) = (mask[bz * Nd + k0 + lane] > 0) ? 1.f : 0.f;
        __syncthreads();

        // ---- grams: D = K . Q^T  (row=k, col=q=lane&31) ----
        f16v aE = {}, aS = {}, aH = {}, aF = {};
        const char* krow = KTg + l31 * 640;
        #pragma unroll
        for (int c = 0; c < 20; c++) {
            s8v a = *(const s8v*)(krow + ((c * 32 + h8 * 16) ^ xorv));
            if (c < 4)       aE = MFMA32x32(a, qf[c], aE);
            else if (c < 8)  aS = MFMA32x32(a, qf[c], aS);
            else if (c < 12) aH = MFMA32x32(a, qf[c], aH);
            else             aF = MFMA32x32(a, qf[c], aF);
        }

        // ---- distances -> logits (per-lane: one q-row, 16 k-values) ----
        float p[16];
        float mt = -INFINITY;
        #pragma unroll
        for (int r = 0; r < 16; r++) {
            int kr = (r & 3) + 8 * (r >> 2) + h4;
            f4v sk = *(const f4v*)(sqkLg + kr * 4);
            float mf = mfLg[kr];
            float sE = sqq.x + sk.x - 2.f * aE[r];
            float dE = sqrtf(fmaxf(sE, 0.f) + EPSf);
            float cv = fminf(fmaxf(aS[r], -1.f + EPSf), 1.f - EPSf);
            float ax = fabsf(cv);
            float pa = sqrtf(1.f - ax) * (1.5707288f + ax * (-0.2121144f + ax * (0.0742610f + ax * (-0.0187293f))));
            float dS = (cv < 0.f) ? (3.14159265f - pa) : pa;
            float d2 = fmaxf(sqq.y + sk.y - 2.f * aH[r], 0.f);
            float den = sqq.z * sk.z + EPSf;
            float arx = fmaxf(1.f + 2.f * d2 / den, 1.f + EPSf);
            float dH = __logf(arx + sqrtf(arx * arx - 1.f));
            float sF = sqq.w + sk.w - 2.f * aF[r];
            float dF = sqrtf(fmaxf(sF, 0.f) + EPSf);
            float lg = -(al * dE + be * dS + ga * dH + de * dF) * itmp;
            p[r] = (mf > 0.5f) ? lg : -1e9f;
            mt = fmaxf(mt, p[r]);
        }
        mt = fmaxf(mt, __shfl_xor(mt, 32, 64));
        float mnew = fmaxf(m_run, mt);
        float sc = __expf(m_run - mnew);
        float ps = 0.f;
        #pragma unroll
        for (int r = 0; r < 16; r++) { p[r] = __expf(p[r] - mnew); ps += p[r]; }
        ps += __shfl_xor(ps, 32, 64);
        l_run = l_run * sc + ps;
        m_run = mnew;

        if (lane < 32) scl[lane] = sc;
        #pragma unroll
        for (int r = 0; r < 16; r++) {
            float s = scl[(r & 3) + 8 * (r >> 2) + h4];
            o0[r] *= s; o1[r] *= s;
        }

        // ---- P relayout: f32 (D-layout) -> bf16 A-frags via cvt_pk + permlane32_swap ----
        unsigned int w0, w1, w2, w3, y0, y1, y2, y3;
        asm("v_cvt_pk_bf16_f32 %0, %1, %2" : "=v"(w0) : "v"(p[0]), "v"(p[1]));
        asm("v_cvt_pk_bf16_f32 %0, %1, %2" : "=v"(w1) : "v"(p[2]), "v"(p[3]));
        asm("v_cvt_pk_bf16_f32 %0, %1, %2" : "=v"(w2) : "v"(p[4]), "v"(p[5]));
        asm("v_cvt_pk_bf16_f32 %0, %1, %2" : "=v"(w3) : "v"(p[6]), "v"(p[7]));
        asm("v_cvt_pk_bf16_f32 %0, %1, %2" : "=v"(y0) : "v"(p[8]), "v"(p[9]));
        asm("v_cvt_pk_bf16_f32 %0, %1, %2" : "=v"(y1) : "v"(p[10]), "v"(p[11]));
        asm("v_cvt_pk_bf16_f32 %0, %1, %2" : "=v"(y2) : "v"(p[12]), "v"(p[13]));
        asm("v_cvt_pk_bf16_f32 %0, %1, %2" : "=v"(y3) : "v"(p[14]), "v"(p[15]));
        asm volatile("v_permlane32_swap_b32 %0, %1" : "+v"(w0), "+v"(w2));
        asm volatile("v_permlane32_swap_b32 %0, %1" : "+v"(w1), "+v"(w3));
        asm volatile("v_permlane32_swap_b32 %0, %1" : "+v"(y0), "+v"(y2));
        asm volatile("v_permlane32_swap_b32 %0, %1" : "+v"(y1), "+v"(y3));
        int4 t1; t1.x = (int)w0; t1.y = (int)w1; t1.z = (int)w2; t1.w = (int)w3;
        int4 t2; t2.x = (int)y0; t2.y = (int)y1; t2.z = (int)y2; t2.w = (int)y3;
        s8v A1 = *(s8v*)&t1;
        s8v A2 = *(s8v*)&t2;

        // ---- PV: O += P . V ----
        const char* vrow0 = VTg + l31 * 144;
        const char* vrow1 = VTg + (32 + l31) * 144;
        s8v b00 = *(const s8v*)(vrow0 + h8 * 16);
        s8v b10 = *(const s8v*)(vrow0 + 32 + h8 * 16);
        s8v b01 = *(const s8v*)(vrow1 + h8 * 16);
        s8v b11 = *(const s8v*)(vrow1 + 32 + h8 * 16);
        o0 = MFMA32x32(A1, b00, o0);
        o0 = MFMA32x32(A2, b10, o0);
        o1 = MFMA32x32(A1, b01, o1);
        o1 = MFMA32x32(A2, b11, o1);
        __syncthreads();
    }

    // ---- merge the two k-parity partials ----
    float* mpar = (float*)(sm + OFF_ML);
    float* lpar = mpar + 64;
    float* aLp = mpar + 128;
    float* bLp = mpar + 192;
    float* Obuf = (float*)sm;   // reuse KT region: 2 x 32 x 64 f32
    if (par == 1) {
        if (lane < 32) { mpar[qsub * 32 + lane] = m_run; lpar[qsub * 32 + lane] = l_run; }
        #pragma unroll
        for (int r = 0; r < 16; r++) {
            int qr = (r & 3) + 8 * (r >> 2) + h4;
            Obuf[(qsub * 32 + qr) * 64 + l31] = o0[r];
            Obuf[(qsub * 32 + qr) * 64 + 32 + l31] = o1[r];
        }
    }
    __syncthreads();
    if (par == 0) {
        float m2 = mpar[qsub * 32 + l31], l2 = lpar[qsub * 32 + l31];
        float M = fmaxf(m_run, m2);
        float s1 = __expf(m_run - M), s2 = __expf(m2 - M);
        float inv = 1.f / (l_run * s1 + l2 * s2);
        if (lane < 32) { aLp[qsub * 32 + lane] = s1 * inv; bLp[qsub * 32 + lane] = s2 * inv; }
        #pragma unroll
        for (int r = 0; r < 16; r++) {
            int qr = (r & 3) + 8 * (r >> 2) + h4;
            float av = aLp[qsub * 32 + qr], bv = bLp[qsub * 32 + qr];
            float r0 = o0[r] * av + Obuf[(qsub * 32 + qr) * 64 + l31] * bv;
            float r1 = o1[r] * av + Obuf[(qsub * 32 + qr) * 64 + 32 + l31] * bv;
            size_t row = (size_t)bz * Nd + q0 + qsub * 32 + qr;
            aout[row * Dd + hh * 64 + l31] = __float2bfloat16(r0);
            aout[row * Dd + hh * 64 + 32 + l31] = __float2bfloat16(r1);
        }
    }
}

extern "C" void kernel_launch(void* const* d_in, const int* in_sizes, int n_in,
                              void* d_out, int out_size, void* d_ws, size_t ws_size,
                              hipStream_t stream) {
    const float* x    = (const float*)d_in[0];
    const int*   mask = (const int*)d_in[1];
    const float* WE   = (const float*)d_in[2];
    const float* bE   = (const float*)d_in[3];
    const float* WS   = (const float*)d_in[4];
    const float* bS   = (const float*)d_in[5];
    const float* WH   = (const float*)d_in[6];
    const float* bH   = (const float*)d_in[7];
    const float* Wrff = (const float*)d_in[8];
    const float* brff = (const float*)d_in[9];
    const float* alpha = (const float*)d_in[10];
    const float* beta  = (const float*)d_in[11];
    const float* gamma_ = (const float*)d_in[12];
    const float* delta = (const float*)d_in[13];
    const float* temperature = (const float*)d_in[14];
    const float* Wv = (const float*)d_in[15];
    const float* bv = (const float*)d_in[16];
    const float* Wo = (const float*)d_in[17];
    const float* bo = (const float*)d_in[18];

    char* ws = (char*)d_ws;
    size_t R = (size_t)Bd * Hh * Nd;                       // 32768
    unsigned short* wit = (unsigned short*)ws;             // R*320*2   = 20971520
    float* sq  = (float*)(ws + 20971520);                  // R*4*4     = 524288
    unsigned short* xb  = (unsigned short*)(ws + 21495808);// 2M*2      = 4194304
    unsigned short* wvb = (unsigned short*)(ws + 25690112);// 1M*2      = 2097152
    unsigned short* wob = (unsigned short*)(ws + 27787264);// 1M*2      = 2097152
    unsigned short* vt  = (unsigned short*)(ws + 29884416);// 2M*2      = 4194304
    __hip_bfloat16* aout = (__hip_bfloat16*)(ws + 34078720); // 2M*2    = 4194304

    witness_kernel<<<dim3(Bd * Hh * (Nd / NPB)), 64, 0, stream>>>(
        x, WE, bE, WS, bS, WH, bH, Wrff, brff, wit, sq, xb);

    cvt_kernel<<<dim3(1024), 256, 0, stream>>>(Wv, wvb, 1 << 20);
    cvt_kernel<<<dim3(1024), 256, 0, stream>>>(Wo, wob, 1 << 20);

    gemm_bf16_kernel<1><<<dim3(16, 16), 256, 0, stream>>>(xb, wvb, bv, nullptr, vt);

    attn_kernel<<<dim3(16, Hh, Bd), 256, 0, stream>>>(
        wit, sq, vt, mask, alpha, beta, gamma_, delta, temperature, aout);

    gemm_bf16_kernel<0><<<dim3(16, 16), 256, 0, stream>>>(
        (const unsigned short*)aout, wob, bo, (float*)d_out, nullptr);
}